// Round 12
// baseline (6426.435 us; speedup 1.0000x reference)
//
#include <hip/hip_runtime.h>
#include <hip/hip_bf16.h>
#include <stdint.h>

typedef __bf16 bf16_t;
typedef bf16_t bf16x8 __attribute__((ext_vector_type(8)));
typedef float  f32x4  __attribute__((ext_vector_type(4)));
typedef float  f32x16 __attribute__((ext_vector_type(16)));

#define I_DIM 512
#define H_DIM 1024
#define B_DIM 64
#define S_DIM 512
#define G4    4096   // 4*H
#define CHUNK 16     // steps per xp ring slot
#define NCHUNK (S_DIM / CHUNK)
#define XPSLOT_ELEMS ((size_t)CHUNK * 64 * G4)   // 1024*4096 bf16 = 8 MB
#define STEP_WGS  64
#define XPROJ_WGS 64

// ---------------- workspace layout (bytes) — total ~34 MB ----------------
#define O_WXT   0x0000000ULL  // [4096][512]  bf16 = 4 MB   (packed WxT, row-major)
#define O_WHTF  0x0400000ULL  // [128][64][64][8] bf16 = 8 MB (Wh in MFMA B-frag order)
#define O_BIAS  0x0C00000ULL  // [4096] f32 = 16 KB
#define O_HBUF  0x0D00000ULL  // 2 slots * 128 KB (h in A-frag order) = 256 KB
#define O_BAR   0x0D40000ULL  // 32 KB counters: half counters + xp_done[] + consumed[]
#define O_XP    0x1200000ULL  // 2 slots * [1024][4096] bf16 = 16 MB

// bar[] u32 indices (64-spaced to avoid false sharing)
#define XPD_IDX(c)  (2048 + (c) * 64)   // xp chunk c published (64 xproj-WG arrivals)
#define CONS_IDX(c) (4096 + (c) * 64)   // xp chunk c consumed  (64 step-WG arrivals)

__device__ __forceinline__ float sigm(float x)      { return 1.f / (1.f + __expf(-x)); }
__device__ __forceinline__ float tanh_fast(float x) { return 1.f - 2.f / (__expf(2.f * x) + 1.f); }

// Packed gate-column permutation: packed col p = q*32 + g*8 + jj  <->  hidden j = q*8+jj, gate g (0:i 1:f 2:g 3:o)

__global__ void k_pack_wx(const float* __restrict__ w0, const float* __restrict__ w1,
                          const float* __restrict__ w2, const float* __restrict__ w3,
                          bf16_t* __restrict__ wxt) {
    int tid = blockIdx.x * 256 + threadIdx.x;
    int k = tid >> 12;
    int p = tid & 4095;
    int q = p >> 5, g = (p >> 3) & 3, jj = p & 7;
    int j = q * 8 + jj;
    const float* src = (g == 0) ? w0 : (g == 1) ? w1 : (g == 2) ? w2 : w3;
    wxt[(size_t)p * I_DIM + k] = (bf16_t)src[k * H_DIM + j];
}

// Wh -> global MFMA B-fragment order: whtf[q][ks][lane][8]
//   element = WhT[p = q*32 + (lane&31)][k = ks*16 + (lane>>5)*8 + e]
__global__ void k_pack_whf(const float* __restrict__ w0, const float* __restrict__ w1,
                           const float* __restrict__ w2, const float* __restrict__ w3,
                           bf16_t* __restrict__ whtf) {
    int idx = blockIdx.x * 256 + threadIdx.x;     // 0..4194303
    int e    = idx & 7;
    int lane = (idx >> 3) & 63;
    int ks   = (idx >> 9) & 63;
    int q    = idx >> 15;                          // 0..127
    int k = ks * 16 + (lane >> 5) * 8 + e;
    int c = lane & 31;
    int g = c >> 3, jj = c & 7;
    int j = q * 8 + jj;
    const float* src = (g == 0) ? w0 : (g == 1) ? w1 : (g == 2) ? w2 : w3;
    whtf[idx] = (bf16_t)src[k * H_DIM + j];
}

__global__ void k_pack_bias(const float* bi0, const float* bh0, const float* bi1, const float* bh1,
                            const float* bi2, const float* bh2, const float* bi3, const float* bh3,
                            float* __restrict__ bias) {
    int p = blockIdx.x * 256 + threadIdx.x;
    int q = p >> 5, g = (p >> 3) & 3, jj = p & 7;
    int j = q * 8 + jj;
    const float* a = (g == 0) ? bi0 : (g == 1) ? bi1 : (g == 2) ? bi2 : bi3;
    const float* b = (g == 0) ? bh0 : (g == 1) ? bh1 : (g == 2) ? bh2 : bh3;
    bias[p] = a[j] + b[j];
}

// ---------------- the whole LSTM in ONE persistent dispatch ----------------
// R18: wave consolidation. R16's widening spilled (per-THREAD state grew);
// here per-thread code/footprint is byte-identical to R13 (VGPR 104) — only
// the blockDim packaging changes. Step = 64 WGs x 1024 thr (16 waves =
// 4 q-block groups x 4 K-quarter waves, each wave running R13's per-wave
// code). Gains vs R13: barrier population 128 -> 32 arrivals/half (flat
// counter, leader->root hop deleted); straggler pool quartered; step WGs
// own 64 dedicated CUs (4 waves/SIMD) and xproj lives on DISJOINT CUs
// (interference removed without spill). Cost: +1 intra-CU __syncthreads
// per step (no L3), 4x redundant per-CU h reads (total traffic unchanged).
// xproj = 64 WGs x 1024 thr, each 4 independent 256-thread quarters running
// the R13 tile code verbatim (identical control flow -> shared barriers
// align); 64x4 = 256 tiles/chunk. Grid 128 blocks -> co-resident trivially.
__global__ __launch_bounds__(1024, 4) void k_mega(
    const float* __restrict__ x, const bf16_t* __restrict__ wxt,
    const float* __restrict__ bias, const bf16_t* __restrict__ whtf,
    bf16_t* __restrict__ xp, bf16_t* __restrict__ hbuf,
    float* __restrict__ out, uint32_t* __restrict__ bar)
{
    __shared__ __align__(16) unsigned char smem[68 * 1024];
    const int tid = threadIdx.x;

    if (blockIdx.x >= STEP_WGS) {
        // ------- xproj path: 4 independent 256-thread quarters per WG -------
        const int xbid = blockIdx.x - STEP_WGS;   // 0..63
        const int qq   = tid >> 8;                // quarter 0..3
        const int qtid = tid & 255;
        bf16_t* Al = (bf16_t*)(smem + qq * 16384);          // 8 KB
        bf16_t* Bl = Al + 4096;                             // 8 KB
        const int tile = xbid * 4 + qq;           // 0..255
        const int n0 = (tile & 31) * 128;
        const int rt = (tile >> 5) * 128;
        const int wv = qtid >> 6;
        const int lane = qtid & 63;
        const int mq = wv >> 1, nq = wv & 1;
        const int l15 = lane & 15, quad = lane >> 4;

        for (int sc = 0; sc < NCHUNK; ++sc) {
            if (sc >= 2) {
                if (tid == 0) {
                    while (__hip_atomic_load(&bar[CONS_IDX(sc - 2)], __ATOMIC_RELAXED,
                                             __HIP_MEMORY_SCOPE_AGENT) < (uint32_t)STEP_WGS)
                        __builtin_amdgcn_s_sleep(2);
                }
                __syncthreads();
            }
            bf16_t* xps = xp + (size_t)(sc & 1) * XPSLOT_ELEMS;
            const int r_base = sc * (CHUNK * 64);

            f32x4 acc[4][4] = {};
            for (int kk = 0; kk < I_DIM; kk += 32) {
                __syncthreads();
                #pragma unroll
                for (int sidx = 0; sidx < 2; ++sidx) {
                    int s = qtid + sidx * 256;
                    int mt = s >> 6, l = s & 63;
                    int m = l & 15, kb = (l >> 4) * 8;
                    int r = r_base + rt + mt * 16 + m;
                    int b = r & 63, si = r >> 6;
                    const float* gp = x + ((size_t)(b * S_DIM + si)) * I_DIM + kk + kb;
                    float4 v0 = *(const float4*)gp;
                    float4 v1 = *(const float4*)(gp + 4);
                    bf16x8 a;
                    a[0] = (bf16_t)v0.x; a[1] = (bf16_t)v0.y; a[2] = (bf16_t)v0.z; a[3] = (bf16_t)v0.w;
                    a[4] = (bf16_t)v1.x; a[5] = (bf16_t)v1.y; a[6] = (bf16_t)v1.z; a[7] = (bf16_t)v1.w;
                    *(bf16x8*)&Al[s * 8] = a;
                    bf16x8 bv = *(const bf16x8*)(wxt + (size_t)(n0 + mt * 16 + m) * I_DIM + kk + kb);
                    *(bf16x8*)&Bl[s * 8] = bv;
                }
                __syncthreads();
                bf16x8 af[4], bfr[4];
                #pragma unroll
                for (int mt = 0; mt < 4; ++mt) af[mt]  = *(bf16x8*)&Al[((mq * 4 + mt) * 64 + lane) * 8];
                #pragma unroll
                for (int nt = 0; nt < 4; ++nt) bfr[nt] = *(bf16x8*)&Bl[((nq * 4 + nt) * 64 + lane) * 8];
                #pragma unroll
                for (int mt = 0; mt < 4; ++mt)
                    #pragma unroll
                    for (int nt = 0; nt < 4; ++nt)
                        acc[mt][nt] = __builtin_amdgcn_mfma_f32_16x16x32_bf16(af[mt], bfr[nt], acc[mt][nt], 0, 0, 0);
            }
            // Epilogue: agent-scope u16 stores (coherent for mid-dispatch read)
            #pragma unroll
            for (int nt = 0; nt < 4; ++nt) {
                int colg = n0 + nq * 64 + nt * 16 + l15;
                float bv = bias[colg];
                #pragma unroll
                for (int mt = 0; mt < 4; ++mt)
                    #pragma unroll
                    for (int r = 0; r < 4; ++r) {
                        int row = rt + mq * 64 + mt * 16 + quad * 4 + r;  // within chunk
                        bf16_t hb = (bf16_t)(acc[mt][nt][r] + bv);
                        __hip_atomic_store((uint16_t*)(xps + (size_t)row * G4 + colg),
                                           __builtin_bit_cast(unsigned short, hb),
                                           __ATOMIC_RELAXED, __HIP_MEMORY_SCOPE_AGENT);
                    }
            }
            asm volatile("s_waitcnt vmcnt(0)" ::: "memory");  // all lanes drained
            __syncthreads();                                   // all quarters drained
            if (tid == 0)
                __hip_atomic_fetch_add(&bar[XPD_IDX(sc)], 1u,
                                       __ATOMIC_RELAXED, __HIP_MEMORY_SCOPE_AGENT);
        }
        return;
    }

    // ---------------- step path: 16 waves = 4 q-blocks x 4 K-quarters ------
    float (*Pl)[4][16][64] = (float (*)[4][16][64])smem;          // 64 KB
    bf16_t (*Hlds)[256]    = (bf16_t (*)[256])(smem + 65536);     // 2 KB

    const int wv   = tid >> 6;                    // 0..15
    const int g    = wv >> 2;                     // q-block group 0..3
    const int w    = wv & 3;                      // K-quarter index
    const int lane = tid & 63;
    const int bid  = blockIdx.x;                  // 0..63
    const int q    = (bid & 31) * 4 + g;          // packed col-block (32 cols)
    const int bh   = bid >> 5;                    // batch half

    const int col  = lane & 31;
    const int ksel = lane >> 5;
    const int gt   = (lane >> 3) & 3;  // 0:i 1:f 2:g 3:o
    const int jj   = lane & 7;

    // Flat per-half arrival counter (monotonic): 32 arrivals/step/half.
    uint32_t* cnt = bar + 1024 + (bh << 6);

    int rrow[4];
    #pragma unroll
    for (int e = 0; e < 4; ++e) rrow[e] = e + 8 * w + 4 * ksel;

    // Loop-invariant B fragments: loaded ONCE for all 512 steps.
    const bf16_t* bb = whtf + ((size_t)q << 15) + (w << 13) + (lane << 3);
    bf16x8 bfr[16];
    #pragma unroll
    for (int i = 0; i < 16; ++i) bfr[i] = *(const bf16x8*)(bb + i * 512);

    // c-state in registers for the ENTIRE sequence (i-gate lanes only).
    float cst[4] = {0.f, 0.f, 0.f, 0.f};

    const int abase = (bh << 15) + (w << 13) + (lane << 3);  // h A-frag base (bf16 elements)

    for (int c = 0; c < NCHUNK; ++c) {
        // Wait for xp chunk c to be fully published (coarse, 1x per 16 steps).
        if (tid == 0) {
            while (__hip_atomic_load(&bar[XPD_IDX(c)], __ATOMIC_RELAXED,
                                     __HIP_MEMORY_SCOPE_AGENT) < (uint32_t)XPROJ_WGS)
                __builtin_amdgcn_s_sleep(2);
        }
        __syncthreads();
        const uint16_t* xpc = (const uint16_t*)(xp + (size_t)(c & 1) * XPSLOT_ELEMS);

        for (int tl = 0; tl < CHUNK; ++tl) {
            const int t = c * CHUNK + tl;

            // h loads upfront — availability guaranteed by previous step's barrier.
            const uint64_t* hsrc = (const uint64_t*)(hbuf + ((t & 1) << 16) + abase);
            uint64_t hl0[16], hl1[16];
            #pragma unroll
            for (int i = 0; i < 16; ++i) {
                hl0[i] = __hip_atomic_load(hsrc + i * 128,     __ATOMIC_RELAXED, __HIP_MEMORY_SCOPE_AGENT);
                hl1[i] = __hip_atomic_load(hsrc + i * 128 + 1, __ATOMIC_RELAXED, __HIP_MEMORY_SCOPE_AGENT);
            }

            // xpr: agent u16 loads (xp produced mid-dispatch on other XCDs)
            bf16_t xpr[4];
            #pragma unroll
            for (int e = 0; e < 4; ++e) {
                unsigned short v = __hip_atomic_load(
                    &xpc[(size_t)(tl * 64 + bh * 32 + rrow[e]) * G4 + q * 32 + col],
                    __ATOMIC_RELAXED, __HIP_MEMORY_SCOPE_AGENT);
                xpr[e] = __builtin_bit_cast(bf16_t, v);
            }

            struct U2 { uint64_t a, b; };
            f32x16 acc0 = {}, acc1 = {}, acc2 = {}, acc3 = {};
            #pragma unroll
            for (int i = 0; i < 16; i += 4) {
                U2 t0{hl0[i + 0], hl1[i + 0]};
                U2 t1{hl0[i + 1], hl1[i + 1]};
                U2 t2{hl0[i + 2], hl1[i + 2]};
                U2 t3{hl0[i + 3], hl1[i + 3]};
                acc0 = __builtin_amdgcn_mfma_f32_32x32x16_bf16(__builtin_bit_cast(bf16x8, t0), bfr[i + 0], acc0, 0, 0, 0);
                acc1 = __builtin_amdgcn_mfma_f32_32x32x16_bf16(__builtin_bit_cast(bf16x8, t1), bfr[i + 1], acc1, 0, 0, 0);
                acc2 = __builtin_amdgcn_mfma_f32_32x32x16_bf16(__builtin_bit_cast(bf16x8, t2), bfr[i + 2], acc2, 0, 0, 0);
                acc3 = __builtin_amdgcn_mfma_f32_32x32x16_bf16(__builtin_bit_cast(bf16x8, t3), bfr[i + 3], acc3, 0, 0, 0);
            }
            f32x16 accs = acc0 + acc1 + acc2 + acc3;

            #pragma unroll
            for (int e = 0; e < 16; ++e) Pl[g][w][e][lane] = accs[e];
            __syncthreads();

            #pragma unroll
            for (int e = 0; e < 4; ++e) {
                int eg = w * 4 + e;
                float pre = Pl[g][0][eg][lane] + Pl[g][1][eg][lane]
                          + Pl[g][2][eg][lane] + Pl[g][3][eg][lane];
                pre += (float)xpr[e];
                float a = (gt == 2) ? tanh_fast(pre) : sigm(pre);

                float fv = __shfl_xor(a, 8, 64);
                float gv = __shfl_xor(a, 16, 64);
                float ov = __shfl_xor(a, 24, 64);
                if (gt == 0) {
                    float cn = fv * cst[e] + a * gv;
                    float hv = ov * tanh_fast(cn);
                    cst[e] = cn;
                    Hlds[g][rrow[e] * 8 + jj] = (bf16_t)hv;
                    if (t == S_DIM - 1) {
                        int rowg = bh * 32 + rrow[e];
                        int j = q * 8 + jj;
                        out[rowg * H_DIM + j] = hv;            // h_T
                        out[65536 + rowg * H_DIM + j] = cn;    // c_T
                    }
                }
            }
            __syncthreads();   // Hlds complete; also fences Pl reuse next step

            // Publish h slices: 4 waves (w==0 of each group), each its q-block.
            if (w == 0) {
                uint64_t v = *(const uint64_t*)&Hlds[g][lane * 4];
                uint64_t* hdst = (uint64_t*)hbuf + (((t + 1) & 1) << 14)
                               + (bh << 13) + (q << 6) + lane;
                __hip_atomic_store(hdst, v, __ATOMIC_RELAXED, __HIP_MEMORY_SCOPE_AGENT);
                if (t < S_DIM - 1)
                    asm volatile("s_waitcnt vmcnt(0)" ::: "memory");  // h store at L3
            }
            if (t < S_DIM - 1) {
                __syncthreads();   // all 4 publishes drained before arrival
                if (tid == 0) {
                    __hip_atomic_fetch_add(cnt, 1u,
                                           __ATOMIC_RELAXED, __HIP_MEMORY_SCOPE_AGENT);
                    uint32_t target = (uint32_t)(32 * (t + 1));
                    while (__hip_atomic_load(cnt, __ATOMIC_RELAXED,
                                             __HIP_MEMORY_SCOPE_AGENT) < target) {}
                }
                __syncthreads();   // release all waves
            }
        }

        // Chunk consumed: xproj may overwrite this xp slot (for chunk c+2).
        if (tid == 0)
            __hip_atomic_fetch_add(&bar[CONS_IDX(c)], 1u,
                                   __ATOMIC_RELAXED, __HIP_MEMORY_SCOPE_AGENT);
    }
}

extern "C" void kernel_launch(void* const* d_in, const int* in_sizes, int n_in,
                              void* d_out, int out_size, void* d_ws, size_t ws_size,
                              hipStream_t stream) {
    const float* x   = (const float*)d_in[0];
    const float* wii = (const float*)d_in[1];
    const float* bii = (const float*)d_in[2];
    const float* whi = (const float*)d_in[3];
    const float* bhi = (const float*)d_in[4];
    const float* wif = (const float*)d_in[5];
    const float* bif = (const float*)d_in[6];
    const float* whf = (const float*)d_in[7];
    const float* bhf = (const float*)d_in[8];
    const float* wig = (const float*)d_in[9];
    const float* big = (const float*)d_in[10];
    const float* whg = (const float*)d_in[11];
    const float* bhg = (const float*)d_in[12];
    const float* wio = (const float*)d_in[13];
    const float* bio = (const float*)d_in[14];
    const float* who = (const float*)d_in[15];
    const float* bho = (const float*)d_in[16];

    char* ws = (char*)d_ws;
    bf16_t*   wxt  = (bf16_t*)(ws + O_WXT);
    bf16_t*   whtf = (bf16_t*)(ws + O_WHTF);
    float*    bias = (float*)(ws + O_BIAS);
    bf16_t*   hbuf = (bf16_t*)(ws + O_HBUF);
    uint32_t* bar  = (uint32_t*)(ws + O_BAR);
    bf16_t*   xp   = (bf16_t*)(ws + O_XP);

    hipMemsetAsync(hbuf, 0, 256 * 1024, stream);   // both h slots = 0 (h0)
    hipMemsetAsync(bar,  0, 32 * 1024, stream);    // all counters (reset each replay)

    k_pack_wx<<<8192, 256, 0, stream>>>(wii, wif, wig, wio, wxt);
    k_pack_whf<<<16384, 256, 0, stream>>>(whi, whf, whg, who, whtf);
    k_pack_bias<<<16, 256, 0, stream>>>(bii, bhi, bif, bhf, big, bhg, bio, bho, bias);

    float* out = (float*)d_out;
    void* args[] = { (void*)&x, (void*)&wxt, (void*)&bias, (void*)&whtf,
                     (void*)&xp, (void*)&hbuf, (void*)&out, (void*)&bar };
    hipError_t err = hipLaunchCooperativeKernel((const void*)k_mega,
                                                dim3(STEP_WGS + XPROJ_WGS), dim3(1024),
                                                args, 0, stream);
    if (err != hipSuccess) {
        // Plain-launch fallback: 128 blocks x 1024 thr on 256 CUs (capacity
        // >= 1 block/CU) — all blocks co-resident regardless of dispatch order.
        k_mega<<<STEP_WGS + XPROJ_WGS, 1024, 0, stream>>>(x, wxt, bias, whtf,
                                                          xp, hbuf, out, bar);
    }
}

// Round 13
// 3431.465 us; speedup vs baseline: 1.8728x; 1.8728x over previous
//
#include <hip/hip_runtime.h>
#include <hip/hip_bf16.h>
#include <stdint.h>

typedef __bf16 bf16_t;
typedef bf16_t bf16x8 __attribute__((ext_vector_type(8)));
typedef float  f32x4  __attribute__((ext_vector_type(4)));
typedef float  f32x16 __attribute__((ext_vector_type(16)));

#define I_DIM 512
#define H_DIM 1024
#define B_DIM 64
#define S_DIM 512
#define G4    4096   // 4*H
#define CHUNK 16     // steps per xp ring slot
#define NCHUNK (S_DIM / CHUNK)
#define XPSLOT_ELEMS ((size_t)CHUNK * 64 * G4)   // 1024*4096 bf16 = 8 MB
#define STEP_BLKS  128
#define XPROJ_BLKS 128

// ---------------- workspace layout (bytes) — total ~34 MB ----------------
#define O_WXT   0x0000000ULL  // [4096][512]  bf16 = 4 MB   (packed WxT, row-major)
#define O_WHTF  0x0400000ULL  // [128][64][64][8] bf16 = 8 MB (Wh in MFMA B-frag order)
#define O_BIAS  0x0C00000ULL  // [4096] f32 = 16 KB
#define O_HBUF  0x0D00000ULL  // 2 slots * 128 KB (h in A-frag order) = 256 KB
#define O_BAR   0x0D40000ULL  // 32 KB counters: tree barrier + xp_done[] + consumed[]
#define O_XP    0x1200000ULL  // 2 slots * [1024][4096] bf16 = 16 MB

// bar[] u32 indices (64-spaced to avoid false sharing)
#define XPD_IDX(c)  (2048 + (c) * 64)   // xp chunk c published (128 xproj-blk arrivals)
#define CONS_IDX(c) (4096 + (c) * 64)   // xp chunk c consumed  (128 step-blk arrivals)

__device__ __forceinline__ float sigm(float x)      { return 1.f / (1.f + __expf(-x)); }
__device__ __forceinline__ float tanh_fast(float x) { return 1.f - 2.f / (__expf(2.f * x) + 1.f); }

// Packed gate-column permutation: packed col p = q*32 + g*8 + jj  <->  hidden j = q*8+jj, gate g (0:i 1:f 2:g 3:o)

__global__ void k_pack_wx(const float* __restrict__ w0, const float* __restrict__ w1,
                          const float* __restrict__ w2, const float* __restrict__ w3,
                          bf16_t* __restrict__ wxt) {
    int tid = blockIdx.x * 256 + threadIdx.x;
    int k = tid >> 12;
    int p = tid & 4095;
    int q = p >> 5, g = (p >> 3) & 3, jj = p & 7;
    int j = q * 8 + jj;
    const float* src = (g == 0) ? w0 : (g == 1) ? w1 : (g == 2) ? w2 : w3;
    wxt[(size_t)p * I_DIM + k] = (bf16_t)src[k * H_DIM + j];
}

// Wh -> global MFMA B-fragment order: whtf[q][ks][lane][8]
//   element = WhT[p = q*32 + (lane&31)][k = ks*16 + (lane>>5)*8 + e]
__global__ void k_pack_whf(const float* __restrict__ w0, const float* __restrict__ w1,
                           const float* __restrict__ w2, const float* __restrict__ w3,
                           bf16_t* __restrict__ whtf) {
    int idx = blockIdx.x * 256 + threadIdx.x;     // 0..4194303
    int e    = idx & 7;
    int lane = (idx >> 3) & 63;
    int ks   = (idx >> 9) & 63;
    int q    = idx >> 15;                          // 0..127
    int k = ks * 16 + (lane >> 5) * 8 + e;
    int c = lane & 31;
    int g = c >> 3, jj = c & 7;
    int j = q * 8 + jj;
    const float* src = (g == 0) ? w0 : (g == 1) ? w1 : (g == 2) ? w2 : w3;
    whtf[idx] = (bf16_t)src[k * H_DIM + j];
}

__global__ void k_pack_bias(const float* bi0, const float* bh0, const float* bi1, const float* bh1,
                            const float* bi2, const float* bh2, const float* bi3, const float* bh3,
                            float* __restrict__ bias) {
    int p = blockIdx.x * 256 + threadIdx.x;
    int q = p >> 5, g = (p >> 3) & 3, jj = p & 7;
    int j = q * 8 + jj;
    const float* a = (g == 0) ? bi0 : (g == 1) ? bi1 : (g == 2) ? bi2 : bi3;
    const float* b = (g == 0) ? bh0 : (g == 1) ? bh1 : (g == 2) ? bh2 : bh3;
    bias[p] = a[j] + b[j];
}

// ---------------- the whole LSTM in ONE persistent dispatch ----------------
// R19: spatial partition, spill cause removed. R16 spilled (per-thread state
// doubled), R18 spilled (launch_bounds(1024,4) halved the register budget:
// VGPR_Count=64). Here per-thread code is byte-identical to R13 AND
// __launch_bounds__(512,2) keeps R13's <=256/wave budget (8 waves/block =
// 2 waves/SIMD). 512-thread blocks = 2 independent 256-thread groups, each
// running R13's step (or xproj) code for its own q-slice (or tile).
// Grid 256 = 128 step + 128 xproj blocks; LDS padded to 84 KB/block ->
// 2x84 > 160 KB -> EXACTLY 1 block/CU -> step and xproj provably on
// disjoint CUs (interference removed); plain-launch co-residency exact.
// Barrier population halves: 64 arrivals/half in 8 groups x 8, leaders ->
// root, poll root >= 8*(t+1) (R13 tree semantics). Cost: +1 intra-CU
// __syncthreads/step to join both groups' h-publishes before arrival.
__global__ __launch_bounds__(512, 2) void k_mega(
    const float* __restrict__ x, const bf16_t* __restrict__ wxt,
    const float* __restrict__ bias, const bf16_t* __restrict__ whtf,
    bf16_t* __restrict__ xp, bf16_t* __restrict__ hbuf,
    float* __restrict__ out, uint32_t* __restrict__ bar)
{
    __shared__ __align__(16) unsigned char smem[84 * 1024];  // forces 1 block/CU
    const int tid = threadIdx.x;

    if (blockIdx.x >= STEP_BLKS) {
        // ------- xproj path: 2 independent 256-thread quarters per block ----
        const int xbid = blockIdx.x - STEP_BLKS;  // 0..127
        const int qq   = tid >> 8;                // quarter 0..1
        const int qtid = tid & 255;
        bf16_t* Al = (bf16_t*)(smem + qq * 16384);          // 8 KB
        bf16_t* Bl = Al + 4096;                             // 8 KB
        const int tile = xbid * 2 + qq;           // 0..255
        const int n0 = (tile & 31) * 128;
        const int rt = (tile >> 5) * 128;
        const int wv = qtid >> 6;
        const int lane = qtid & 63;
        const int mq = wv >> 1, nq = wv & 1;
        const int l15 = lane & 15, quad = lane >> 4;

        for (int sc = 0; sc < NCHUNK; ++sc) {
            // Slot reuse gate: chunk sc writes slot sc&1 (held chunk sc-2).
            if (sc >= 2) {
                if (tid == 0) {
                    while (__hip_atomic_load(&bar[CONS_IDX(sc - 2)], __ATOMIC_RELAXED,
                                             __HIP_MEMORY_SCOPE_AGENT) < (uint32_t)STEP_BLKS)
                        __builtin_amdgcn_s_sleep(2);
                }
                __syncthreads();
            }
            bf16_t* xps = xp + (size_t)(sc & 1) * XPSLOT_ELEMS;
            const int r_base = sc * (CHUNK * 64);

            f32x4 acc[4][4] = {};
            for (int kk = 0; kk < I_DIM; kk += 32) {
                __syncthreads();
                #pragma unroll
                for (int sidx = 0; sidx < 2; ++sidx) {
                    int s = qtid + sidx * 256;
                    int mt = s >> 6, l = s & 63;
                    int m = l & 15, kb = (l >> 4) * 8;
                    int r = r_base + rt + mt * 16 + m;
                    int b = r & 63, si = r >> 6;
                    const float* gp = x + ((size_t)(b * S_DIM + si)) * I_DIM + kk + kb;
                    float4 v0 = *(const float4*)gp;
                    float4 v1 = *(const float4*)(gp + 4);
                    bf16x8 a;
                    a[0] = (bf16_t)v0.x; a[1] = (bf16_t)v0.y; a[2] = (bf16_t)v0.z; a[3] = (bf16_t)v0.w;
                    a[4] = (bf16_t)v1.x; a[5] = (bf16_t)v1.y; a[6] = (bf16_t)v1.z; a[7] = (bf16_t)v1.w;
                    *(bf16x8*)&Al[s * 8] = a;
                    bf16x8 bv = *(const bf16x8*)(wxt + (size_t)(n0 + mt * 16 + m) * I_DIM + kk + kb);
                    *(bf16x8*)&Bl[s * 8] = bv;
                }
                __syncthreads();
                bf16x8 af[4], bfr[4];
                #pragma unroll
                for (int mt = 0; mt < 4; ++mt) af[mt]  = *(bf16x8*)&Al[((mq * 4 + mt) * 64 + lane) * 8];
                #pragma unroll
                for (int nt = 0; nt < 4; ++nt) bfr[nt] = *(bf16x8*)&Bl[((nq * 4 + nt) * 64 + lane) * 8];
                #pragma unroll
                for (int mt = 0; mt < 4; ++mt)
                    #pragma unroll
                    for (int nt = 0; nt < 4; ++nt)
                        acc[mt][nt] = __builtin_amdgcn_mfma_f32_16x16x32_bf16(af[mt], bfr[nt], acc[mt][nt], 0, 0, 0);
            }
            // Epilogue: agent-scope u16 stores (coherent for mid-dispatch read)
            #pragma unroll
            for (int nt = 0; nt < 4; ++nt) {
                int colg = n0 + nq * 64 + nt * 16 + l15;
                float bv = bias[colg];
                #pragma unroll
                for (int mt = 0; mt < 4; ++mt)
                    #pragma unroll
                    for (int r = 0; r < 4; ++r) {
                        int row = rt + mq * 64 + mt * 16 + quad * 4 + r;  // within chunk
                        bf16_t hb = (bf16_t)(acc[mt][nt][r] + bv);
                        __hip_atomic_store((uint16_t*)(xps + (size_t)row * G4 + colg),
                                           __builtin_bit_cast(unsigned short, hb),
                                           __ATOMIC_RELAXED, __HIP_MEMORY_SCOPE_AGENT);
                    }
            }
            asm volatile("s_waitcnt vmcnt(0)" ::: "memory");  // all lanes drained
            __syncthreads();                                   // both quarters drained
            if (tid == 0)
                __hip_atomic_fetch_add(&bar[XPD_IDX(sc)], 1u,
                                       __ATOMIC_RELAXED, __HIP_MEMORY_SCOPE_AGENT);
        }
        return;
    }

    // ---------------- step path: 2 groups x (R13 per-wave code) ------------
    float (*Pl)[4][16][64] = (float (*)[4][16][64])smem;              // 32 KB
    bf16_t (*Hlds)[256]    = (bf16_t (*)[256])(smem + 32768);         // 1 KB

    const int g     = tid >> 8;                   // q-group 0..1
    const int qtid  = tid & 255;
    const int w     = qtid >> 6;                  // K-quarter index
    const int lane  = qtid & 63;
    const int bid   = blockIdx.x;                 // 0..127
    const int qpair = bid & 63;
    const int q     = qpair * 2 + g;              // packed col-block (32 cols)
    const int bh    = bid >> 6;                   // batch half

    const int col  = lane & 31;
    const int ksel = lane >> 5;
    const int gt   = (lane >> 3) & 3;  // 0:i 1:f 2:g 3:o
    const int jj   = lane & 7;

    // Per-half barrier tree (monotonic u32, 64-spaced):
    //   group[bh][gi]: bar[(bh*8+gi)*64], gi = qpair&7, 8 arrivals/episode
    //   root[bh]:      bar[1024 + bh*64], 8 leader increments/episode
    uint32_t* grp  = bar + ((bh * 8 + (qpair & 7)) << 6);
    uint32_t* root = bar + 1024 + (bh << 6);

    int rrow[4];
    #pragma unroll
    for (int e = 0; e < 4; ++e) rrow[e] = e + 8 * w + 4 * ksel;

    // Loop-invariant B fragments: loaded ONCE for all 512 steps.
    const bf16_t* bb = whtf + ((size_t)q << 15) + (w << 13) + (lane << 3);
    bf16x8 bfr[16];
    #pragma unroll
    for (int i = 0; i < 16; ++i) bfr[i] = *(const bf16x8*)(bb + i * 512);

    // c-state in registers for the ENTIRE sequence (i-gate lanes only).
    float cst[4] = {0.f, 0.f, 0.f, 0.f};

    const int abase = (bh << 15) + (w << 13) + (lane << 3);  // h A-frag base (bf16 elements)

    for (int c = 0; c < NCHUNK; ++c) {
        // Wait for xp chunk c to be fully published (coarse, 1x per 16 steps).
        if (tid == 0) {
            while (__hip_atomic_load(&bar[XPD_IDX(c)], __ATOMIC_RELAXED,
                                     __HIP_MEMORY_SCOPE_AGENT) < (uint32_t)XPROJ_BLKS)
                __builtin_amdgcn_s_sleep(2);
        }
        __syncthreads();
        const uint16_t* xpc = (const uint16_t*)(xp + (size_t)(c & 1) * XPSLOT_ELEMS);

        for (int tl = 0; tl < CHUNK; ++tl) {
            const int t = c * CHUNK + tl;

            // h loads upfront — availability guaranteed by previous step's barrier.
            const uint64_t* hsrc = (const uint64_t*)(hbuf + ((t & 1) << 16) + abase);
            uint64_t hl0[16], hl1[16];
            #pragma unroll
            for (int i = 0; i < 16; ++i) {
                hl0[i] = __hip_atomic_load(hsrc + i * 128,     __ATOMIC_RELAXED, __HIP_MEMORY_SCOPE_AGENT);
                hl1[i] = __hip_atomic_load(hsrc + i * 128 + 1, __ATOMIC_RELAXED, __HIP_MEMORY_SCOPE_AGENT);
            }

            // xpr: agent u16 loads (xp produced mid-dispatch on other XCDs)
            bf16_t xpr[4];
            #pragma unroll
            for (int e = 0; e < 4; ++e) {
                unsigned short v = __hip_atomic_load(
                    &xpc[(size_t)(tl * 64 + bh * 32 + rrow[e]) * G4 + q * 32 + col],
                    __ATOMIC_RELAXED, __HIP_MEMORY_SCOPE_AGENT);
                xpr[e] = __builtin_bit_cast(bf16_t, v);
            }

            struct U2 { uint64_t a, b; };
            f32x16 acc0 = {}, acc1 = {}, acc2 = {}, acc3 = {};
            #pragma unroll
            for (int i = 0; i < 16; i += 4) {
                U2 t0{hl0[i + 0], hl1[i + 0]};
                U2 t1{hl0[i + 1], hl1[i + 1]};
                U2 t2{hl0[i + 2], hl1[i + 2]};
                U2 t3{hl0[i + 3], hl1[i + 3]};
                acc0 = __builtin_amdgcn_mfma_f32_32x32x16_bf16(__builtin_bit_cast(bf16x8, t0), bfr[i + 0], acc0, 0, 0, 0);
                acc1 = __builtin_amdgcn_mfma_f32_32x32x16_bf16(__builtin_bit_cast(bf16x8, t1), bfr[i + 1], acc1, 0, 0, 0);
                acc2 = __builtin_amdgcn_mfma_f32_32x32x16_bf16(__builtin_bit_cast(bf16x8, t2), bfr[i + 2], acc2, 0, 0, 0);
                acc3 = __builtin_amdgcn_mfma_f32_32x32x16_bf16(__builtin_bit_cast(bf16x8, t3), bfr[i + 3], acc3, 0, 0, 0);
            }
            f32x16 accs = acc0 + acc1 + acc2 + acc3;

            #pragma unroll
            for (int e = 0; e < 16; ++e) Pl[g][w][e][lane] = accs[e];
            __syncthreads();

            #pragma unroll
            for (int e = 0; e < 4; ++e) {
                int eg = w * 4 + e;
                float pre = Pl[g][0][eg][lane] + Pl[g][1][eg][lane]
                          + Pl[g][2][eg][lane] + Pl[g][3][eg][lane];
                pre += (float)xpr[e];
                float a = (gt == 2) ? tanh_fast(pre) : sigm(pre);

                float fv = __shfl_xor(a, 8, 64);
                float gv = __shfl_xor(a, 16, 64);
                float ov = __shfl_xor(a, 24, 64);
                if (gt == 0) {
                    float cn = fv * cst[e] + a * gv;
                    float hv = ov * tanh_fast(cn);
                    cst[e] = cn;
                    Hlds[g][rrow[e] * 8 + jj] = (bf16_t)hv;
                    if (t == S_DIM - 1) {
                        int rowg = bh * 32 + rrow[e];
                        int j = q * 8 + jj;
                        out[rowg * H_DIM + j] = hv;            // h_T
                        out[65536 + rowg * H_DIM + j] = cn;    // c_T
                    }
                }
            }
            __syncthreads();   // Hlds complete; also fences Pl reuse next step

            // Publish h slices (wave 0 of each group), drain in-wave.
            if (w == 0) {
                uint64_t v = *(const uint64_t*)&Hlds[g][lane * 4];
                uint64_t* hdst = (uint64_t*)hbuf + (((t + 1) & 1) << 14)
                               + (bh << 13) + (q << 6) + lane;
                __hip_atomic_store(hdst, v, __ATOMIC_RELAXED, __HIP_MEMORY_SCOPE_AGENT);
                if (t < S_DIM - 1)
                    asm volatile("s_waitcnt vmcnt(0)" ::: "memory");  // h store at L3
            }
            if (t < S_DIM - 1) {
                __syncthreads();   // join both groups' drained publishes
                if (tid == 0) {
                    uint32_t old = __hip_atomic_fetch_add(grp, 1u,
                                                          __ATOMIC_RELAXED, __HIP_MEMORY_SCOPE_AGENT);
                    if ((old & 7u) == 7u)                        // 8 arrivals -> leader
                        __hip_atomic_fetch_add(root, 1u,
                                               __ATOMIC_RELAXED, __HIP_MEMORY_SCOPE_AGENT);
                    uint32_t target = (uint32_t)(8 * (t + 1));
                    while (__hip_atomic_load(root, __ATOMIC_RELAXED,
                                             __HIP_MEMORY_SCOPE_AGENT) < target) {}
                }
                __syncthreads();   // release all waves
            }
        }

        // Chunk consumed: xproj may overwrite this xp slot (for chunk c+2).
        if (tid == 0)
            __hip_atomic_fetch_add(&bar[CONS_IDX(c)], 1u,
                                   __ATOMIC_RELAXED, __HIP_MEMORY_SCOPE_AGENT);
    }
}

extern "C" void kernel_launch(void* const* d_in, const int* in_sizes, int n_in,
                              void* d_out, int out_size, void* d_ws, size_t ws_size,
                              hipStream_t stream) {
    const float* x   = (const float*)d_in[0];
    const float* wii = (const float*)d_in[1];
    const float* bii = (const float*)d_in[2];
    const float* whi = (const float*)d_in[3];
    const float* bhi = (const float*)d_in[4];
    const float* wif = (const float*)d_in[5];
    const float* bif = (const float*)d_in[6];
    const float* whf = (const float*)d_in[7];
    const float* bhf = (const float*)d_in[8];
    const float* wig = (const float*)d_in[9];
    const float* big = (const float*)d_in[10];
    const float* whg = (const float*)d_in[11];
    const float* bhg = (const float*)d_in[12];
    const float* wio = (const float*)d_in[13];
    const float* bio = (const float*)d_in[14];
    const float* who = (const float*)d_in[15];
    const float* bho = (const float*)d_in[16];

    char* ws = (char*)d_ws;
    bf16_t*   wxt  = (bf16_t*)(ws + O_WXT);
    bf16_t*   whtf = (bf16_t*)(ws + O_WHTF);
    float*    bias = (float*)(ws + O_BIAS);
    bf16_t*   hbuf = (bf16_t*)(ws + O_HBUF);
    uint32_t* bar  = (uint32_t*)(ws + O_BAR);
    bf16_t*   xp   = (bf16_t*)(ws + O_XP);

    hipMemsetAsync(hbuf, 0, 256 * 1024, stream);   // both h slots = 0 (h0)
    hipMemsetAsync(bar,  0, 32 * 1024, stream);    // all counters (reset each replay)

    k_pack_wx<<<8192, 256, 0, stream>>>(wii, wif, wig, wio, wxt);
    k_pack_whf<<<16384, 256, 0, stream>>>(whi, whf, whg, who, whtf);
    k_pack_bias<<<16, 256, 0, stream>>>(bii, bhi, bif, bhf, big, bhg, bio, bho, bias);

    float* out = (float*)d_out;
    void* args[] = { (void*)&x, (void*)&wxt, (void*)&bias, (void*)&whtf,
                     (void*)&xp, (void*)&hbuf, (void*)&out, (void*)&bar };
    hipError_t err = hipLaunchCooperativeKernel((const void*)k_mega,
                                                dim3(STEP_BLKS + XPROJ_BLKS), dim3(512),
                                                args, 0, stream);
    if (err != hipSuccess) {
        // Plain-launch fallback: 256 blocks x 84 KB LDS -> exactly 1 block/CU
        // on 256 CUs; all blocks co-resident regardless of dispatch order.
        k_mega<<<STEP_BLKS + XPROJ_BLKS, 512, 0, stream>>>(x, wxt, bias, whtf,
                                                           xp, hbuf, out, bar);
    }
}